// Round 3
// baseline (683.206 us; speedup 1.0000x reference)
//
#include <hip/hip_runtime.h>
#include <math.h>

// d: (262144, 256) float32, row-major. s[j] = sum_i d[i][j]^2,
// out = 0.001 * sqrt(sum_j (s[j]-1)^2). Memory-bound: 268 MB stream,
// roofline ~43 us @ 6.3 TB/s.

#define NROW   262144
#define NCOL   256
#define NCOLV  64        // columns in float4 units
#define GRID   2048      // 8 blocks/CU on 256 CUs
#define ITERS  (NROW / 4 / GRID)   // 32 four-row groups per block

typedef float v4f __attribute__((ext_vector_type(4)));  // native vec for nt-load

// ws layout: [0..255] float g_col, [256] uint done-counter. memset 2048 B.

__global__ __launch_bounds__(256) void colsq_kernel(
        const v4f* __restrict__ d, float* __restrict__ g_col,
        unsigned* __restrict__ cnt, float* __restrict__ out) {
    const int tid   = threadIdx.x;
    const int c4    = tid & 63;   // float4 column index 0..63
    const int r_off = tid >> 6;   // row within 4-row group, 0..3

    v4f acc = (v4f)(0.f);

    // Each block streams a contiguous 128 KiB chunk; one iter = 4 rows = 4 KiB
    // of wave-contiguous dwordx4 loads. unroll 8 -> 8 loads in flight/thread.
    const size_t base_rg = (size_t)blockIdx.x * ITERS;
#pragma unroll 8
    for (int i = 0; i < ITERS; ++i) {
        const size_t row = (base_rg + i) * 4 + r_off;
        const v4f v = __builtin_nontemporal_load(&d[row * NCOLV + c4]);
        acc += v * v;
    }

    // Block reduce across the 4 r_off groups via LDS (2-way bank alias = free).
    __shared__ float lds[4 * NCOL];
    v4f* l4 = (v4f*)lds;
    l4[r_off * NCOLV + c4] = acc;          // contiguous b128 per wave
    __syncthreads();
    float s = lds[tid] + lds[NCOL + tid] + lds[2 * NCOL + tid] + lds[3 * NCOL + tid];
    atomicAdd(&g_col[tid], s);             // 256 addresses, 2048 adds each

    // Last-block finalize: release fence -> counter -> acquire fence.
    __shared__ int is_last;
    __threadfence();                        // make our g_col adds visible (release)
    if (tid == 0) {
        unsigned old = atomicAdd(cnt, 1u);
        is_last = (old == GRID - 1);
    }
    __syncthreads();
    if (is_last) {
        __threadfence();                    // acquire
        // atomic read (fetch_add 0) guarantees we see all blocks' adds.
        float sj = atomicAdd(&g_col[tid], 0.0f);
        float diff = sj - 1.0f;
        float v = diff * diff;
#pragma unroll
        for (int off = 32; off > 0; off >>= 1)
            v += __shfl_down(v, off, 64);
        __shared__ float ws[4];
        if ((tid & 63) == 0) ws[tid >> 6] = v;
        __syncthreads();
        if (tid == 0)
            out[0] = 0.001f * sqrtf(ws[0] + ws[1] + ws[2] + ws[3]);
    }
}

extern "C" void kernel_launch(void* const* d_in, const int* in_sizes, int n_in,
                              void* d_out, int out_size, void* d_ws, size_t ws_size,
                              hipStream_t stream) {
    const v4f* d     = (const v4f*)d_in[0];
    float* g_col     = (float*)d_ws;                 // 256 floats
    unsigned* cnt    = (unsigned*)((char*)d_ws + NCOL * sizeof(float));
    float* out       = (float*)d_out;

    (void)hipMemsetAsync(d_ws, 0, 2048, stream);     // zero g_col + counter
    colsq_kernel<<<GRID, 256, 0, stream>>>(d, g_col, cnt, out);
}

// Round 4
// 357.027 us; speedup vs baseline: 1.9136x; 1.9136x over previous
//
#include <hip/hip_runtime.h>
#include <math.h>

// d: (262144, 256) float32, row-major. s[j] = sum_i d[i][j]^2,
// out = 0.001 * sqrt(sum_j (s[j]-1)^2). Memory-bound: 268 MB stream,
// roofline ~43 us @ 6.3 TB/s (less if L3-resident half streams faster).
//
// R3 lesson: __builtin_nontemporal_load (nt) made this 8x SLOWER (400 us,
// constant even when fully L3-served) — nt bypasses cache allocate and
// throttles outstanding requests. Plain cached loads only.

#define NROW   262144
#define NCOL   256
#define NCOLV  64        // columns in float4 units
#define GRID   2048      // 8 blocks/CU on 256 CUs
#define ITERS  (NROW / 4 / GRID)   // 32 four-row groups per block

// ws layout: [0..255] float g_col. memset 1024 B.

__global__ __launch_bounds__(256) void colsq_kernel(
        const float4* __restrict__ d, float* __restrict__ g_col) {
    const int tid   = threadIdx.x;
    const int c4    = tid & 63;   // float4 column index 0..63
    const int r_off = tid >> 6;   // row within 4-row group, 0..3

    float4 acc = make_float4(0.f, 0.f, 0.f, 0.f);

    // Each block streams a contiguous 128 KiB chunk; one iter = 4 rows = 4 KiB
    // of wave-contiguous dwordx4 loads. unroll 8 -> 8 loads in flight/thread.
    const size_t base_rg = (size_t)blockIdx.x * ITERS;
#pragma unroll 8
    for (int i = 0; i < ITERS; ++i) {
        const size_t row = (base_rg + i) * 4 + r_off;
        const float4 v = d[row * NCOLV + c4];
        acc.x += v.x * v.x;
        acc.y += v.y * v.y;
        acc.z += v.z * v.z;
        acc.w += v.w * v.w;
    }

    // Block reduce across the 4 r_off groups via LDS (2-way bank alias = free).
    __shared__ float lds[4 * NCOL];
    float4* l4 = (float4*)lds;
    l4[r_off * NCOLV + c4] = acc;          // contiguous b128 per wave
    __syncthreads();
    float s = lds[tid] + lds[NCOL + tid] + lds[2 * NCOL + tid] + lds[3 * NCOL + tid];
    atomicAdd(&g_col[tid], s);             // 256 addresses, 2048 adds each
}

__global__ __launch_bounds__(256) void finalize_kernel(
        const float* __restrict__ g_col, float* __restrict__ out) {
    const int tid = threadIdx.x;
    float diff = g_col[tid] - 1.0f;
    float v = diff * diff;
#pragma unroll
    for (int off = 32; off > 0; off >>= 1)
        v += __shfl_down(v, off, 64);
    __shared__ float ws[4];
    if ((tid & 63) == 0) ws[tid >> 6] = v;
    __syncthreads();
    if (tid == 0)
        out[0] = 0.001f * sqrtf(ws[0] + ws[1] + ws[2] + ws[3]);
}

extern "C" void kernel_launch(void* const* d_in, const int* in_sizes, int n_in,
                              void* d_out, int out_size, void* d_ws, size_t ws_size,
                              hipStream_t stream) {
    const float4* d  = (const float4*)d_in[0];
    float* g_col     = (float*)d_ws;                 // 256 floats
    float* out       = (float*)d_out;

    (void)hipMemsetAsync(g_col, 0, NCOL * sizeof(float), stream);
    colsq_kernel<<<GRID, 256, 0, stream>>>(d, g_col);
    finalize_kernel<<<1, 256, 0, stream>>>(g_col, out);
}